// Round 8
// baseline (124.489 us; speedup 1.0000x reference)
//
#include <hip/hip_runtime.h>
#include <math.h>

#define N_SAMPLES 131072
#define NUM_CLASSES 128
#define NB 256
#define MAX_FPR 0.7f          // 1 - RECALL_THRESHOLD
#define NBLK 1024             // fused grid: 4 blocks/CU
#define ROWS_PER_BLK 128      // N_SAMPLES / NBLK  (max per-bin count 128 < 256: u8-safe)
#define HPITCH 65             // class row pitch in LDS u32 words (64 + 1 pad)
#define PART_WORDS (NUM_CLASSES * 64)    // 8192 u32 (u8x4) per block partial

typedef unsigned long long u64;
typedef unsigned int u32;

// bin(x; L) = floor((x - L + 14) * 16) clamped to [0,255]. Identical
// expression for the positive and the all histogram.
__device__ __forceinline__ int bin_of(float x, float off /* (14-lse)*16 */) {
    int b = (int)__fmaf_rn(x, 16.0f, off);
    return min(max(b, 0), NB - 1);
}

// ---------------------------------------------------------------------------
// Fused phase 1: block = 128 rows, full 128-class x 256-bin LDS histogram
// packed as u8x4 per u32 word (counts <= 128, no carry) -> 33 KB LDS ->
// 4 blocks/CU, 32 waves = full occupancy (the r7 limiter).
// 16 lanes/row, 8 cols/lane via two coalesced float4 loads; 2-deep pipeline.
// Swizzle: class c's word w at c*65 + ((w + j) & 63), j=(c>>2)&15 ->
// bank = (5j + q + w) mod 32, 16 distinct banks across j (gcd(5,32)=1).
// ---------------------------------------------------------------------------
__global__ __launch_bounds__(512, 8) void fused_kernel(
    const float* __restrict__ pred, const int* __restrict__ tgt,
    u32* __restrict__ hPos,      // [128][256] global, pre-zeroed
    u32* __restrict__ part,      // [NBLK][8192] non-atomic u8x4 partials
    float* __restrict__ acc)     // [0] = ce sum
{
    __shared__ u32 h32[NUM_CLASSES * HPITCH];   // 33280 B
    __shared__ float wsum[8];

    const int tid  = threadIdx.x;
    const int w    = tid >> 6;        // wave 0..7
    const int lane = tid & 63;
    const int j    = lane & 15;       // lane within row
    const int rs   = lane >> 4;       // row sub-index 0..3

    for (int i = tid; i < NUM_CLASSES * HPITCH; i += 512) h32[i] = 0u;
    __syncthreads();

    const int rowBase = blockIdx.x * ROWS_PER_BLK + w * 4 + rs;
    float acc_lse = 0.0f, acc_xt = 0.0f, acc_sx = 0.0f;

    // 2-deep pipeline over 4 passes (row stride 32 per pass)
    const float* r0p = pred + (size_t)rowBase * 128;
    float4 a0 = *(const float4*)(r0p + j * 4);
    float4 a1 = *(const float4*)(r0p + 64 + j * 4);
    int    ta = tgt[rowBase];
    const float* r1p = r0p + (size_t)32 * 128;
    float4 c0 = *(const float4*)(r1p + j * 4);
    float4 c1 = *(const float4*)(r1p + 64 + j * 4);
    int    tb = tgt[rowBase + 32];

    #pragma unroll
    for (int p = 0; p < 4; p++) {
        float4 n0, n1; int tn = 0;
        if (p < 2) {
            const float* rn = pred + (size_t)(rowBase + (p + 2) * 32) * 128;
            n0 = *(const float4*)(rn + j * 4);
            n1 = *(const float4*)(rn + 64 + j * 4);
            tn = tgt[rowBase + (p + 2) * 32];
        }

        float e = __expf(a0.x) + __expf(a0.y) + __expf(a0.z) + __expf(a0.w)
                + __expf(a1.x) + __expf(a1.y) + __expf(a1.z) + __expf(a1.w);
        #pragma unroll
        for (int o = 1; o < 16; o <<= 1) e += __shfl_xor(e, o);
        const float lse = __logf(e);
        const float off = (14.0f - lse) * 16.0f;

        const float xv[8] = {a0.x, a0.y, a0.z, a0.w, a1.x, a1.y, a1.z, a1.w};
        #pragma unroll
        for (int q = 0; q < 8; q++) {
            const int c = (q < 4) ? (j * 4 + q) : (64 + j * 4 + (q - 4));
            const int b = bin_of(xv[q], off);
            const int word = ((b >> 2) + j) & 63;       // swizzle: 16 banks
            atomicAdd(&h32[c * HPITCH + word], 1u << ((b & 3) * 8));
        }

        acc_sx  += (xv[0] + xv[1] + xv[2] + xv[3])
                 + (xv[4] + xv[5] + xv[6] + xv[7]);
        acc_lse += lse * 0.0625f;     // 16 lanes/row each add lse/16

        {   // exactly one of the row's 16 lanes owns the target column
            const int t = ta;
            float xt; bool hit = false;
            if ((t >> 2) == j)                        { xt = xv[t & 3];       hit = true; }
            else if (t >= 64 && ((t - 64) >> 2) == j) { xt = xv[4 + (t & 3)]; hit = true; }
            if (hit) {
                acc_xt += xt;
                atomicAdd(&hPos[(t << 8) | bin_of(xt, off)], 1u);
            }
        }

        a0 = c0; a1 = c1; ta = tb;
        c0 = n0; c1 = n1; tb = tn;
    }

    // CE: sum(lse) - 0.9*sum(x_t) - (0.1/128)*sum(x)
    float ce = acc_lse - 0.9f * acc_xt - (0.1f / 128.0f) * acc_sx;
    #pragma unroll
    for (int o = 32; o; o >>= 1) ce += __shfl_xor(ce, o);
    if (lane == 0) wsum[w] = ce;
    __syncthreads();
    if (tid == 0) {
        float s = 0.0f;
        #pragma unroll
        for (int i = 0; i < 8; i++) s += wsum[i];
        atomicAdd(&acc[0], s);
    }

    // un-rotating partial writeout: linear i = c*64 + w  (u8x4 words)
    u32* outp = part + (size_t)blockIdx.x * PART_WORDS;
    for (int i = tid; i < PART_WORDS; i += 512) {
        const int c = i >> 6, bw = i & 63;
        outp[i] = h32[c * HPITCH + ((bw + ((c >> 2) & 15)) & 63)];
    }
}

// ---------------------------------------------------------------------------
// Reducer + finalize: one 256-thread block per class. Thread t owns u8x4
// word (t&63) over quarter (t>>6) of the NBLK partials (coalesced 256B/wave,
// 8-deep MLP), unpacks u8 fields, LDS-atomic merge into 256 u32 bins, wave 0
// does the descending-bin scan + clipped trapezoidal pAUC. Last-done block
// writes the final scalar.
// ---------------------------------------------------------------------------
__global__ __launch_bounds__(256) void pauc_reduce(
    const u32* __restrict__ part,
    const u32* __restrict__ hPos,
    float* __restrict__ acc,          // [0]=ce,[1]=pauc,[2]=valid,[3]=done ctr
    float* __restrict__ out)
{
    __shared__ __align__(16) u32 sBins[NB];

    const int k  = blockIdx.x;
    const int t  = threadIdx.x;
    const int w  = t & 63;            // u8x4 word within class row
    const int qt = t >> 6;            // quarter of the partials

    sBins[t] = 0u;
    __syncthreads();

    u32 a0 = 0u, a1 = 0u, a2 = 0u, a3 = 0u;
    const u32* p0 = part + (size_t)(qt * (NBLK / 4)) * PART_WORDS + k * 64 + w;
    #pragma unroll 8
    for (int b = 0; b < NBLK / 4; b++) {
        const u32 q = p0[(size_t)b * PART_WORDS];
        a0 += q & 0xffu; a1 += (q >> 8) & 0xffu;
        a2 += (q >> 16) & 0xffu; a3 += q >> 24;
    }
    atomicAdd(&sBins[4 * w + 0], a0);
    atomicAdd(&sBins[4 * w + 1], a1);
    atomicAdd(&sBins[4 * w + 2], a2);
    atomicAdd(&sBins[4 * w + 3], a3);
    __syncthreads();

    if (t < 64) {
        const int lane = t;
        // lane owns DESCENDING bins 255-4l..252-4l = uint4 at word 63-l, reversed
        const uint4 q  = ((const uint4*)sBins)[63 - lane];
        const u32 a[4] = {q.w, q.z, q.y, q.x};
        const uint4 pq = ((const uint4*)(hPos + (k << 8)))[63 - lane];
        const u32 p[4] = {pq.w, pq.z, pq.y, pq.x};

        const u32 la = a[0] + a[1] + a[2] + a[3];
        const u32 lp = p[0] + p[1] + p[2] + p[3];

        u32 ia = la, ip = lp;
        #pragma unroll
        for (int o = 1; o < 64; o <<= 1) {
            const u32 tA = __shfl_up(ia, o);
            const u32 tP = __shfl_up(ip, o);
            if (lane >= o) { ia += tA; ip += tP; }
        }
        const u32 P = __shfl(ip, 63);
        const u32 T = __shfl(ia, 63);
        const float Pm = fmaxf((float)P, 1.0f);
        const float Fm = fmaxf((float)(T - P), 1.0f);

        int cumA = (int)(ia - la), cumP = (int)(ip - lp);  // exclusive prefixes
        float contrib = 0.0f;
        #pragma unroll
        for (int i = 0; i < 4; i++) {
            const int f = (int)a[i] - (int)p[i];
            if (f > 0) {
                const float fpr0 = (float)(cumA - cumP) / Fm;
                if (fpr0 < MAX_FPR) {
                    const float tpr0 = (float)cumP / Pm;
                    const float tpr1 = (float)(cumP + (int)p[i]) / Pm;
                    const float fpr1 = (float)(cumA - cumP + f) / Fm;
                    if (fpr1 <= MAX_FPR) {
                        contrib += (fpr1 - fpr0) * 0.5f * (tpr0 + tpr1);
                    } else {
                        const float tfrac = (MAX_FPR - fpr0) / (fpr1 - fpr0);
                        const float tprc  = tpr0 + tfrac * (tpr1 - tpr0);
                        contrib += (MAX_FPR - fpr0) * 0.5f * (tpr0 + tprc);
                    }
                }
            }
            cumA += (int)a[i]; cumP += (int)p[i];
        }

        #pragma unroll
        for (int o = 32; o; o >>= 1) contrib += __shfl_xor(contrib, o);

        if (lane == 0) {
            if (P > 0u) {
                atomicAdd(&acc[1], contrib);
                atomicAdd(&acc[2], 1.0f);
            }
            __threadfence();
            const u32 done = atomicAdd((u32*)(acc + 3), 1u);
            if (done == NUM_CLASSES - 1) {
                const float ces = atomicAdd(&acc[0], 0.0f);
                const float ps  = atomicAdd(&acc[1], 0.0f);
                const float vs  = atomicAdd(&acc[2], 0.0f);
                const float cem  = ces * (1.0f / (float)N_SAMPLES);
                const float pauc = ps / fmaxf(vs, 1.0f);
                out[0] = 0.5f * cem + 0.5f * (1.0f - pauc * pauc);
            }
        }
    }
}

extern "C" void kernel_launch(void* const* d_in, const int* in_sizes, int n_in,
                              void* d_out, int out_size, void* d_ws, size_t ws_size,
                              hipStream_t stream)
{
    const float* pred = (const float*)d_in[0];
    const int*   tgt  = (const int*)d_in[1];

    char* ws = (char*)d_ws;
    u32*   hPos = (u32*)ws;                    // 128 KB
    float* acc  = (float*)(ws + 131072);       // 32 B (acc[0..3])
    u32*   part = (u32*)(ws + 262144);         // 32 MB u8x4 partials

    hipMemsetAsync(ws, 0, 131072 + 32, stream);   // hPos + acc

    fused_kernel<<<NBLK, 512, 0, stream>>>(pred, tgt, hPos, part, acc);
    pauc_reduce<<<NUM_CLASSES, 256, 0, stream>>>(part, hPos, acc, (float*)d_out);
}

// Round 9
// 120.254 us; speedup vs baseline: 1.0352x; 1.0352x over previous
//
#include <hip/hip_runtime.h>
#include <math.h>

#define N_SAMPLES 131072
#define NUM_CLASSES 128
#define NB 256
#define MAX_FPR 0.7f          // 1 - RECALL_THRESHOLD
#define NBLK 512              // fused grid: 2 blocks/CU -> 32 waves (100% occ)
#define ROWS_PER_BLK 256      // max per-bin count/block = 256 -> u16-safe
#define HPITCH 129            // class row pitch in LDS u32 words (128 + 1 pad)
#define PART_WORDS (NUM_CLASSES * 128)   // 16384 u32 (u16x2) per block partial

typedef unsigned long long u64;
typedef unsigned int u32;

// bin(x; L) = floor((x - L + 14) * 16) clamped to [0,255]. Identical
// expression for the positive and the all histogram.
__device__ __forceinline__ int bin_of(float x, float off /* (14-lse)*16 */) {
    int b = (int)__fmaf_rn(x, 16.0f, off);
    return min(max(b, 0), NB - 1);
}

// One pass: 8 lanes per row, 16 cols per lane (4 float4 at cols 4j, 32+4j,
// 64+4j, 96+4j). 3-step 8-lane shuffle reduce for lse (half r7's shuffle
// latency per element), then 16 LDS atomics. Classes 32g+4j+q hit 8 distinct
// banks across j (4j mod 32), so no swizzle needed.
__device__ __forceinline__ void do_pass(
    float4 a0, float4 a1, float4 a2, float4 a3, int t, int j,
    u32* h32, u32* __restrict__ hPos,
    float& acc_lse, float& acc_xt, float& acc_sx)
{
    const float xv[16] = {a0.x, a0.y, a0.z, a0.w, a1.x, a1.y, a1.z, a1.w,
                          a2.x, a2.y, a2.z, a2.w, a3.x, a3.y, a3.z, a3.w};
    float e = 0.0f;
    #pragma unroll
    for (int q = 0; q < 16; q++) e += __expf(xv[q]);
    #pragma unroll
    for (int o = 1; o < 8; o <<= 1) e += __shfl_xor(e, o);
    const float lse = __logf(e);
    const float off = (14.0f - lse) * 16.0f;

    #pragma unroll
    for (int q = 0; q < 16; q++) {
        const int c = ((q >> 2) << 5) + (j << 2) + (q & 3);   // 32g + 4j + q
        const int b = bin_of(xv[q], off);
        atomicAdd(&h32[c * HPITCH + (b >> 1)], (b & 1) ? 65536u : 1u);
    }

    float sx = 0.0f;
    #pragma unroll
    for (int q = 0; q < 16; q++) sx += xv[q];
    acc_sx += sx;
    if (j == 0) acc_lse += lse;

    // target column t = 32g + 4j' + q: owned by lane with j' = (t&31)>>2
    if (((t & 31) >> 2) == j) {
        const float xt = xv[((t >> 5) << 2) + (t & 3)];
        acc_xt += xt;
        atomicAdd(&hPos[(t << 8) | bin_of(xt, off)], 1u);
    }
}

// ---------------------------------------------------------------------------
// Fused phase 1: block = 256 rows, full 128x256 LDS histogram (u16 pairs,
// 66 KB). Grid 512 x 1024 thr -> 2 blocks/CU = 32 waves = full occupancy
// (r7 had 16). launch_bounds(1024,8) caps VGPRs at 64 so 8 waves/SIMD fit.
// 2 passes; ALL loads (8 dwordx4/lane) issue in the prologue -> max MLP.
// ---------------------------------------------------------------------------
__global__ __launch_bounds__(1024, 8) void fused_kernel(
    const float* __restrict__ pred, const int* __restrict__ tgt,
    u32* __restrict__ hPos,      // [128][256] global, pre-zeroed
    u32* __restrict__ part,      // [NBLK][16384] non-atomic u16x2 partials
    float* __restrict__ acc)     // [0] = ce sum
{
    __shared__ u32 h32[NUM_CLASSES * HPITCH];   // 66048 B
    __shared__ float wsum[16];

    const int tid  = threadIdx.x;
    const int w    = tid >> 6;        // wave 0..15
    const int lane = tid & 63;
    const int j    = lane & 7;        // lane within row
    const int rs   = lane >> 3;       // row sub-index 0..7

    for (int i = tid; i < NUM_CLASSES * HPITCH; i += 1024) h32[i] = 0u;
    __syncthreads();

    const int row0 = blockIdx.x * ROWS_PER_BLK + w * 8 + rs;   // pass 0
    const int row1 = row0 + 128;                               // pass 1

    // prologue: all 8 dwordx4 loads in flight
    const float* rp0 = pred + (size_t)row0 * 128 + j * 4;
    const float* rp1 = pred + (size_t)row1 * 128 + j * 4;
    const float4 a0 = *(const float4*)(rp0);
    const float4 a1 = *(const float4*)(rp0 + 32);
    const float4 a2 = *(const float4*)(rp0 + 64);
    const float4 a3 = *(const float4*)(rp0 + 96);
    const float4 b0 = *(const float4*)(rp1);
    const float4 b1 = *(const float4*)(rp1 + 32);
    const float4 b2 = *(const float4*)(rp1 + 64);
    const float4 b3 = *(const float4*)(rp1 + 96);
    const int t0 = tgt[row0];
    const int t1 = tgt[row1];

    float acc_lse = 0.0f, acc_xt = 0.0f, acc_sx = 0.0f;
    do_pass(a0, a1, a2, a3, t0, j, h32, hPos, acc_lse, acc_xt, acc_sx);
    do_pass(b0, b1, b2, b3, t1, j, h32, hPos, acc_lse, acc_xt, acc_sx);

    // CE: sum(lse) - 0.9*sum(x_t) - (0.1/128)*sum(x)
    float ce = acc_lse - 0.9f * acc_xt - (0.1f / 128.0f) * acc_sx;
    #pragma unroll
    for (int o = 32; o; o >>= 1) ce += __shfl_xor(ce, o);
    if (lane == 0) wsum[w] = ce;
    __syncthreads();
    if (tid == 0) {
        float s = 0.0f;
        #pragma unroll
        for (int i = 0; i < 16; i++) s += wsum[i];
        atomicAdd(&acc[0], s);
    }

    // partial writeout: linear i = c*128 + word
    u32* outp = part + (size_t)blockIdx.x * PART_WORDS;
    for (int i = tid; i < PART_WORDS; i += 1024)
        outp[i] = h32[(i >> 7) * HPITCH + (i & 127)];
}

// ---------------------------------------------------------------------------
// Reducer + finalize: one 256-thread block per class. Thread t sums packed
// word (t&127) over half the NBLK partials (coalesced streams, 8-deep MLP),
// LDS merge, wave 0 does the descending-bin scan + clipped trapezoidal pAUC.
// Last-done block writes the final scalar.
// ---------------------------------------------------------------------------
__global__ __launch_bounds__(256) void pauc_reduce(
    const u32* __restrict__ part,
    const u32* __restrict__ hPos,
    float* __restrict__ acc,          // [0]=ce,[1]=pauc,[2]=valid,[3]=done ctr
    float* __restrict__ out)
{
    __shared__ __align__(16) u32 sA[NB];

    const int k    = blockIdx.x;
    const int t    = threadIdx.x;
    const int w    = t & 127;         // packed word within class row
    const int half = t >> 7;          // which half of the block-partials

    u32 lo = 0u, hi = 0u;
    const u32* p0 = part + (size_t)(half * (NBLK / 2)) * PART_WORDS
                         + k * 128 + w;
    #pragma unroll 8
    for (int b = 0; b < NBLK / 2; b++) {
        const u32 q = p0[(size_t)b * PART_WORDS];
        lo += q & 0xffffu; hi += q >> 16;
    }
    if (half == 0) { sA[2 * w] = lo; sA[2 * w + 1] = hi; }
    __syncthreads();
    if (half == 1) { sA[2 * w] += lo; sA[2 * w + 1] += hi; }
    __syncthreads();

    if (t < 64) {
        const int lane = t;
        // lane owns DESCENDING bins 255-4l..252-4l = uint4 at word 63-l, reversed
        const uint4 q  = ((const uint4*)sA)[63 - lane];
        const u32 a[4] = {q.w, q.z, q.y, q.x};
        const uint4 pq = ((const uint4*)(hPos + (k << 8)))[63 - lane];
        const u32 p[4] = {pq.w, pq.z, pq.y, pq.x};

        const u32 la = a[0] + a[1] + a[2] + a[3];
        const u32 lp = p[0] + p[1] + p[2] + p[3];

        u32 ia = la, ip = lp;
        #pragma unroll
        for (int o = 1; o < 64; o <<= 1) {
            const u32 tA = __shfl_up(ia, o);
            const u32 tP = __shfl_up(ip, o);
            if (lane >= o) { ia += tA; ip += tP; }
        }
        const u32 P = __shfl(ip, 63);
        const u32 T = __shfl(ia, 63);
        const float Pm = fmaxf((float)P, 1.0f);
        const float Fm = fmaxf((float)(T - P), 1.0f);

        int cumA = (int)(ia - la), cumP = (int)(ip - lp);  // exclusive prefixes
        float contrib = 0.0f;
        #pragma unroll
        for (int i = 0; i < 4; i++) {
            const int f = (int)a[i] - (int)p[i];
            if (f > 0) {
                const float fpr0 = (float)(cumA - cumP) / Fm;
                if (fpr0 < MAX_FPR) {
                    const float tpr0 = (float)cumP / Pm;
                    const float tpr1 = (float)(cumP + (int)p[i]) / Pm;
                    const float fpr1 = (float)(cumA - cumP + f) / Fm;
                    if (fpr1 <= MAX_FPR) {
                        contrib += (fpr1 - fpr0) * 0.5f * (tpr0 + tpr1);
                    } else {
                        const float tfrac = (MAX_FPR - fpr0) / (fpr1 - fpr0);
                        const float tprc  = tpr0 + tfrac * (tpr1 - tpr0);
                        contrib += (MAX_FPR - fpr0) * 0.5f * (tpr0 + tprc);
                    }
                }
            }
            cumA += (int)a[i]; cumP += (int)p[i];
        }

        #pragma unroll
        for (int o = 32; o; o >>= 1) contrib += __shfl_xor(contrib, o);

        if (lane == 0) {
            if (P > 0u) {
                atomicAdd(&acc[1], contrib);
                atomicAdd(&acc[2], 1.0f);
            }
            __threadfence();
            const u32 done = atomicAdd((u32*)(acc + 3), 1u);
            if (done == NUM_CLASSES - 1) {
                const float ces = atomicAdd(&acc[0], 0.0f);
                const float ps  = atomicAdd(&acc[1], 0.0f);
                const float vs  = atomicAdd(&acc[2], 0.0f);
                const float cem  = ces * (1.0f / (float)N_SAMPLES);
                const float pauc = ps / fmaxf(vs, 1.0f);
                out[0] = 0.5f * cem + 0.5f * (1.0f - pauc * pauc);
            }
        }
    }
}

extern "C" void kernel_launch(void* const* d_in, const int* in_sizes, int n_in,
                              void* d_out, int out_size, void* d_ws, size_t ws_size,
                              hipStream_t stream)
{
    const float* pred = (const float*)d_in[0];
    const int*   tgt  = (const int*)d_in[1];

    char* ws = (char*)d_ws;
    u32*   hPos = (u32*)ws;                    // 128 KB
    float* acc  = (float*)(ws + 131072);       // 32 B (acc[0..3])
    u32*   part = (u32*)(ws + 262144);         // 32 MB u16x2 partials

    hipMemsetAsync(ws, 0, 131072 + 32, stream);   // hPos + acc

    fused_kernel<<<NBLK, 1024, 0, stream>>>(pred, tgt, hPos, part, acc);
    pauc_reduce<<<NUM_CLASSES, 256, 0, stream>>>(part, hPos, acc, (float*)d_out);
}

// Round 10
// 110.060 us; speedup vs baseline: 1.1311x; 1.0926x over previous
//
#include <hip/hip_runtime.h>
#include <math.h>

#define N_SAMPLES 131072
#define NUM_CLASSES 128
#define NB 128                // bins (width 1/8 over s in [-14, 2])
#define MAX_FPR 0.7f          // 1 - RECALL_THRESHOLD
#define NBLK 512              // fused grid: 2 blocks/CU -> 32 waves/CU
#define ROWS_PER_BLK 256      // max per-bin count/block = 256 -> u16-safe
#define HPITCH 65             // class row pitch in LDS u32 words (64 + 1 pad)
#define PART_WORDS (NUM_CLASSES * 64)    // 8192 u32 (u16x2) per block partial

typedef unsigned long long u64;
typedef unsigned int u32;

// bin(x; L) = floor((x - L + 14) * 8) clamped to [0,127]. Identical
// expression for the positive and the all histogram.
__device__ __forceinline__ int bin_of(float x, float off /* (14-lse)*8 */) {
    int b = (int)__fmaf_rn(x, 8.0f, off);
    return min(max(b, 0), NB - 1);
}

// ---------------------------------------------------------------------------
// Fused phase 1 — the r7 body (48 VGPR, known-good) with NB=128:
// 33 KB LDS -> 2 blocks/CU = 32 waves (r7 had 16). Block = 256 rows,
// 16 lanes/row, 8 cols/lane via two coalesced float4 loads, 2-deep pipeline,
// 4 passes. Swizzle: class c's word w at c*65 + ((w + j) & 63), j=(c>>2)&15
// -> bank = (c + w + j) mod 32 spans 16 distinct banks (gcd(5,32)=1).
// Partials: 512 x 32 KB = 16 MB (same reduce traffic as r7, unlike r9).
// ---------------------------------------------------------------------------
__global__ __launch_bounds__(1024, 8) void fused_kernel(
    const float* __restrict__ pred, const int* __restrict__ tgt,
    u32* __restrict__ hPos,      // [128][128] global, pre-zeroed
    u32* __restrict__ part,      // [NBLK][8192] non-atomic u16x2 partials
    float* __restrict__ acc)     // [0] = ce sum
{
    __shared__ u32 h32[NUM_CLASSES * HPITCH];   // 33280 B
    __shared__ float wsum[16];

    const int tid  = threadIdx.x;
    const int w    = tid >> 6;        // wave 0..15
    const int lane = tid & 63;
    const int j    = lane & 15;       // lane within row
    const int rs   = lane >> 4;       // row sub-index 0..3

    for (int i = tid; i < NUM_CLASSES * HPITCH; i += 1024) h32[i] = 0u;
    __syncthreads();

    const int rowBase = blockIdx.x * ROWS_PER_BLK + w * 4 + rs;
    float acc_lse = 0.0f, acc_xt = 0.0f, acc_sx = 0.0f;

    // 2-deep pipeline over 4 passes (row stride 64 per pass)
    const float* r0p = pred + (size_t)rowBase * 128;
    float4 a0 = *(const float4*)(r0p + j * 4);
    float4 a1 = *(const float4*)(r0p + 64 + j * 4);
    int    ta = tgt[rowBase];
    const float* r1p = r0p + (size_t)64 * 128;
    float4 c0 = *(const float4*)(r1p + j * 4);
    float4 c1 = *(const float4*)(r1p + 64 + j * 4);
    int    tb = tgt[rowBase + 64];

    #pragma unroll
    for (int p = 0; p < 4; p++) {
        float4 n0, n1; int tn = 0;
        if (p < 2) {
            const float* rn = pred + (size_t)(rowBase + (p + 2) * 64) * 128;
            n0 = *(const float4*)(rn + j * 4);
            n1 = *(const float4*)(rn + 64 + j * 4);
            tn = tgt[rowBase + (p + 2) * 64];
        }

        float e = __expf(a0.x) + __expf(a0.y) + __expf(a0.z) + __expf(a0.w)
                + __expf(a1.x) + __expf(a1.y) + __expf(a1.z) + __expf(a1.w);
        #pragma unroll
        for (int o = 1; o < 16; o <<= 1) e += __shfl_xor(e, o);
        const float lse = __logf(e);
        const float off = (14.0f - lse) * 8.0f;

        const float xv[8] = {a0.x, a0.y, a0.z, a0.w, a1.x, a1.y, a1.z, a1.w};
        #pragma unroll
        for (int q = 0; q < 8; q++) {
            const int c = (q < 4) ? (j * 4 + q) : (64 + j * 4 + (q - 4));
            const int b = bin_of(xv[q], off);
            const int word = ((b >> 1) + j) & 63;       // swizzle: 16 banks
            atomicAdd(&h32[c * HPITCH + word], (b & 1) ? 65536u : 1u);
        }

        acc_sx  += (xv[0] + xv[1] + xv[2] + xv[3])
                 + (xv[4] + xv[5] + xv[6] + xv[7]);
        acc_lse += lse * 0.0625f;     // 16 lanes/row each add lse/16

        {   // exactly one of the row's 16 lanes owns the target column
            const int t = ta;
            float xt; bool hit = false;
            if ((t >> 2) == j)                        { xt = xv[t & 3];       hit = true; }
            else if (t >= 64 && ((t - 64) >> 2) == j) { xt = xv[4 + (t & 3)]; hit = true; }
            if (hit) {
                acc_xt += xt;
                atomicAdd(&hPos[(t << 7) | bin_of(xt, off)], 1u);
            }
        }

        a0 = c0; a1 = c1; ta = tb;
        c0 = n0; c1 = n1; tb = tn;
    }

    // CE: sum(lse) - 0.9*sum(x_t) - (0.1/128)*sum(x)
    float ce = acc_lse - 0.9f * acc_xt - (0.1f / 128.0f) * acc_sx;
    #pragma unroll
    for (int o = 32; o; o >>= 1) ce += __shfl_xor(ce, o);
    if (lane == 0) wsum[w] = ce;
    __syncthreads();
    if (tid == 0) {
        float s = 0.0f;
        #pragma unroll
        for (int i = 0; i < 16; i++) s += wsum[i];
        atomicAdd(&acc[0], s);
    }

    // un-rotating partial writeout: linear i = c*64 + bw
    u32* outp = part + (size_t)blockIdx.x * PART_WORDS;
    for (int i = tid; i < PART_WORDS; i += 1024) {
        const int c = i >> 6, bw = i & 63;
        outp[i] = h32[c * HPITCH + ((bw + ((c >> 2) & 15)) & 63)];
    }
}

// ---------------------------------------------------------------------------
// Reducer + finalize: one 256-thread block per class. Thread t sums packed
// word (t&63) over quarter (t>>6) of the NBLK partials (coalesced streams,
// 8-deep MLP), LDS-atomic merge into 128 u32 bins, wave 0 does the
// descending-bin scan (2 bins/lane) + clipped trapezoidal pAUC. Last-done
// block writes the final scalar.
// ---------------------------------------------------------------------------
__global__ __launch_bounds__(256) void pauc_reduce(
    const u32* __restrict__ part,
    const u32* __restrict__ hPos,
    float* __restrict__ acc,          // [0]=ce,[1]=pauc,[2]=valid,[3]=done ctr
    float* __restrict__ out)
{
    __shared__ __align__(16) u32 sBins[NB];

    const int k  = blockIdx.x;
    const int t  = threadIdx.x;
    const int w  = t & 63;            // packed u16x2 word within class row
    const int qt = t >> 6;            // quarter of the partials

    if (t < NB) sBins[t] = 0u;
    __syncthreads();

    u32 lo = 0u, hi = 0u;
    const u32* p0 = part + (size_t)(qt * (NBLK / 4)) * PART_WORDS + k * 64 + w;
    #pragma unroll 8
    for (int b = 0; b < NBLK / 4; b++) {
        const u32 q = p0[(size_t)b * PART_WORDS];
        lo += q & 0xffffu; hi += q >> 16;
    }
    atomicAdd(&sBins[2 * w + 0], lo);
    atomicAdd(&sBins[2 * w + 1], hi);
    __syncthreads();

    if (t < 64) {
        const int lane = t;
        // lane owns DESCENDING bins 127-2l (a[0]) and 126-2l (a[1]):
        // = uint2 at ascending word 63-l, reversed.
        const uint2 q  = ((const uint2*)sBins)[63 - lane];
        const u32 a[2] = {q.y, q.x};
        const uint2 pq = ((const uint2*)(hPos + (k << 7)))[63 - lane];
        const u32 p[2] = {pq.y, pq.x};

        const u32 la = a[0] + a[1];
        const u32 lp = p[0] + p[1];

        u32 ia = la, ip = lp;
        #pragma unroll
        for (int o = 1; o < 64; o <<= 1) {
            const u32 tA = __shfl_up(ia, o);
            const u32 tP = __shfl_up(ip, o);
            if (lane >= o) { ia += tA; ip += tP; }
        }
        const u32 P = __shfl(ip, 63);
        const u32 T = __shfl(ia, 63);
        const float Pm = fmaxf((float)P, 1.0f);
        const float Fm = fmaxf((float)(T - P), 1.0f);

        int cumA = (int)(ia - la), cumP = (int)(ip - lp);  // exclusive prefixes
        float contrib = 0.0f;
        #pragma unroll
        for (int i = 0; i < 2; i++) {
            const int f = (int)a[i] - (int)p[i];
            if (f > 0) {
                const float fpr0 = (float)(cumA - cumP) / Fm;
                if (fpr0 < MAX_FPR) {
                    const float tpr0 = (float)cumP / Pm;
                    const float tpr1 = (float)(cumP + (int)p[i]) / Pm;
                    const float fpr1 = (float)(cumA - cumP + f) / Fm;
                    if (fpr1 <= MAX_FPR) {
                        contrib += (fpr1 - fpr0) * 0.5f * (tpr0 + tpr1);
                    } else {
                        const float tfrac = (MAX_FPR - fpr0) / (fpr1 - fpr0);
                        const float tprc  = tpr0 + tfrac * (tpr1 - tpr0);
                        contrib += (MAX_FPR - fpr0) * 0.5f * (tpr0 + tprc);
                    }
                }
            }
            cumA += (int)a[i]; cumP += (int)p[i];
        }

        #pragma unroll
        for (int o = 32; o; o >>= 1) contrib += __shfl_xor(contrib, o);

        if (lane == 0) {
            if (P > 0u) {
                atomicAdd(&acc[1], contrib);
                atomicAdd(&acc[2], 1.0f);
            }
            __threadfence();
            const u32 done = atomicAdd((u32*)(acc + 3), 1u);
            if (done == NUM_CLASSES - 1) {
                const float ces = atomicAdd(&acc[0], 0.0f);
                const float ps  = atomicAdd(&acc[1], 0.0f);
                const float vs  = atomicAdd(&acc[2], 0.0f);
                const float cem  = ces * (1.0f / (float)N_SAMPLES);
                const float pauc = ps / fmaxf(vs, 1.0f);
                out[0] = 0.5f * cem + 0.5f * (1.0f - pauc * pauc);
            }
        }
    }
}

extern "C" void kernel_launch(void* const* d_in, const int* in_sizes, int n_in,
                              void* d_out, int out_size, void* d_ws, size_t ws_size,
                              hipStream_t stream)
{
    const float* pred = (const float*)d_in[0];
    const int*   tgt  = (const int*)d_in[1];

    char* ws = (char*)d_ws;
    u32*   hPos = (u32*)ws;                    // 64 KB ([128][128] u32)
    float* acc  = (float*)(ws + 65536);        // 32 B (acc[0..3])
    u32*   part = (u32*)(ws + 131072);         // 16 MB u16x2 partials

    hipMemsetAsync(ws, 0, 65536 + 32, stream);    // hPos + acc

    fused_kernel<<<NBLK, 1024, 0, stream>>>(pred, tgt, hPos, part, acc);
    pauc_reduce<<<NUM_CLASSES, 256, 0, stream>>>(part, hPos, acc, (float*)d_out);
}

// Round 11
// 103.437 us; speedup vs baseline: 1.2035x; 1.0640x over previous
//
#include <hip/hip_runtime.h>
#include <math.h>

#define N_SAMPLES 131072
#define NUM_CLASSES 128
#define NB 64                 // bins (width 1/4 over s in [-14, 2])
#define MAX_FPR 0.7f          // 1 - RECALL_THRESHOLD
#define NBLK 512              // fused grid: 2 blocks/CU
#define ROWS_PER_BLK 256      // max per-bin count/block = 256 -> u16-safe
#define HP 33                 // class row pitch in LDS u32 words (32 + 1 pad)
#define PART_WORDS (NUM_CLASSES * 32 * 2)   // all + pos = 8192 u32 per block

typedef unsigned int u32;

// bin(x; L) = floor((x - L + 14) * 4) clamped to [0,63]. Identical expression
// for the positive and the all histogram (same kernel, same registers).
__device__ __forceinline__ int bin_of(float x, float off /* (14-lse)*4 */) {
    int b = (int)__fmaf_rn(x, 4.0f, off);
    return min(max(b, 0), NB - 1);
}

// ---------------------------------------------------------------------------
// Fused phase 1 — r10's proven body, NB=64, TWO LDS hists (all + positives):
// 34 KB LDS -> 2 blocks/CU. Block = 256 rows, 16 lanes/row, 8 cols/lane via
// two coalesced float4 loads, 2-deep pipeline, 4 passes.
// Swizzle: word = ((b>>1)+j)&31 -> bank = (5j+q+(b>>1)) mod 32, 16 distinct
// banks across j (gcd(5,32)=1). NOTHING in d_ws needs pre-zeroing:
//  - partials are fully overwritten (plain stores)
//  - ceArr[block] is a plain store
//  - doneCtr is zeroed here by block 0 (only the NEXT kernel reads it)
// ---------------------------------------------------------------------------
__global__ __launch_bounds__(1024, 8) void fused_kernel(
    const float* __restrict__ pred, const int* __restrict__ tgt,
    u32* __restrict__ part,      // [NBLK][8192]: [0..4095]=all, [4096..]=pos
    float* __restrict__ ceArr,   // [NBLK] plain-stored CE partials
    u32* __restrict__ doneCtr)
{
    __shared__ u32 hA[NUM_CLASSES * HP];   // all hist, u16x2  (16.9 KB)
    __shared__ u32 hP[NUM_CLASSES * HP];   // pos hist, u16x2  (16.9 KB)
    __shared__ float wsum[16];

    const int tid  = threadIdx.x;
    const int w    = tid >> 6;        // wave 0..15
    const int lane = tid & 63;
    const int j    = lane & 15;       // lane within row
    const int rs   = lane >> 4;       // row sub-index 0..3

    for (int i = tid; i < NUM_CLASSES * HP; i += 1024) { hA[i] = 0u; hP[i] = 0u; }
    if (blockIdx.x == 0 && tid == 0) *doneCtr = 0u;
    __syncthreads();

    const int rowBase = blockIdx.x * ROWS_PER_BLK + w * 4 + rs;
    float acc_lse = 0.0f, acc_xt = 0.0f, acc_sx = 0.0f;

    // 2-deep pipeline over 4 passes (row stride 64 per pass)
    const float* r0p = pred + (size_t)rowBase * 128;
    float4 a0 = *(const float4*)(r0p + j * 4);
    float4 a1 = *(const float4*)(r0p + 64 + j * 4);
    int    ta = tgt[rowBase];
    const float* r1p = r0p + (size_t)64 * 128;
    float4 c0 = *(const float4*)(r1p + j * 4);
    float4 c1 = *(const float4*)(r1p + 64 + j * 4);
    int    tb = tgt[rowBase + 64];

    #pragma unroll
    for (int p = 0; p < 4; p++) {
        float4 n0, n1; int tn = 0;
        if (p < 2) {
            const float* rn = pred + (size_t)(rowBase + (p + 2) * 64) * 128;
            n0 = *(const float4*)(rn + j * 4);
            n1 = *(const float4*)(rn + 64 + j * 4);
            tn = tgt[rowBase + (p + 2) * 64];
        }

        float e = __expf(a0.x) + __expf(a0.y) + __expf(a0.z) + __expf(a0.w)
                + __expf(a1.x) + __expf(a1.y) + __expf(a1.z) + __expf(a1.w);
        #pragma unroll
        for (int o = 1; o < 16; o <<= 1) e += __shfl_xor(e, o);
        const float lse = __logf(e);
        const float off = (14.0f - lse) * 4.0f;

        const float xv[8] = {a0.x, a0.y, a0.z, a0.w, a1.x, a1.y, a1.z, a1.w};
        #pragma unroll
        for (int q = 0; q < 8; q++) {
            const int c = (q < 4) ? (j * 4 + q) : (64 + j * 4 + (q - 4));
            const int b = bin_of(xv[q], off);
            const int word = ((b >> 1) + j) & 31;       // swizzle: 16 banks
            atomicAdd(&hA[c * HP + word], (b & 1) ? 65536u : 1u);
        }

        acc_sx  += (xv[0] + xv[1] + xv[2] + xv[3])
                 + (xv[4] + xv[5] + xv[6] + xv[7]);
        acc_lse += lse * 0.0625f;     // 16 lanes/row each add lse/16

        {   // exactly one of the row's 16 lanes owns the target column
            const int t = ta;
            float xt; bool hit = false;
            if ((t >> 2) == j)                        { xt = xv[t & 3];       hit = true; }
            else if (t >= 64 && ((t - 64) >> 2) == j) { xt = xv[4 + (t & 3)]; hit = true; }
            if (hit) {
                acc_xt += xt;
                const int bp = bin_of(xt, off);
                atomicAdd(&hP[t * HP + (((bp >> 1) + j) & 31)],
                          (bp & 1) ? 65536u : 1u);
            }
        }

        a0 = c0; a1 = c1; ta = tb;
        c0 = n0; c1 = n1; tb = tn;
    }

    // CE partial: sum(lse) - 0.9*sum(x_t) - (0.1/128)*sum(x)
    float ce = acc_lse - 0.9f * acc_xt - (0.1f / 128.0f) * acc_sx;
    #pragma unroll
    for (int o = 32; o; o >>= 1) ce += __shfl_xor(ce, o);
    if (lane == 0) wsum[w] = ce;
    __syncthreads();
    if (tid == 0) {
        float s = 0.0f;
        #pragma unroll
        for (int i = 0; i < 16; i++) s += wsum[i];
        ceArr[blockIdx.x] = s;       // plain store, no init needed
    }

    // un-rotating writeout: linear i = c*32 + bw; all then pos
    u32* outp = part + (size_t)blockIdx.x * PART_WORDS;
    for (int i = tid; i < 4096; i += 1024) {
        const int c = i >> 5, bw = i & 31;
        const int src = c * HP + ((bw + ((c >> 2) & 15)) & 31);
        outp[i]        = hA[src];
        outp[4096 + i] = hP[src];
    }
}

// ---------------------------------------------------------------------------
// Reducer + finalize: one 256-thread block per class. Thread t sums packed
// word (t&31) of both hists over slice (t>>5) of the 512 partials (coalesced,
// 8-deep MLP), LDS-atomic merge into 64 u32 bins each, then one lane per bin
// (descending) does the scan + clipped trapezoidal pAUC. Results go to plain
// arrays; the last-ticket block gathers everything and writes the scalar.
// ---------------------------------------------------------------------------
__global__ __launch_bounds__(256) void pauc_reduce(
    const u32* __restrict__ part, const float* __restrict__ ceArr,
    float* __restrict__ paucArr, float* __restrict__ validArr,
    u32* __restrict__ doneCtr, float* __restrict__ out)
{
    __shared__ u32 aB[NB], pB[NB];

    const int k  = blockIdx.x;
    const int t  = threadIdx.x;
    const int w  = t & 31;            // packed u16x2 word within class row
    const int sl = t >> 5;            // slice of the partials (8 x 64)

    if (t < NB) { aB[t] = 0u; pB[t] = 0u; }
    __syncthreads();

    u32 alo = 0u, ahi = 0u, plo = 0u, phi = 0u;
    const u32* base = part + (size_t)(sl * 64) * PART_WORDS + k * 32 + w;
    #pragma unroll 8
    for (int b = 0; b < 64; b++) {
        const u32 qa = base[(size_t)b * PART_WORDS];
        const u32 qp = base[(size_t)b * PART_WORDS + 4096];
        alo += qa & 0xffffu; ahi += qa >> 16;
        plo += qp & 0xffffu; phi += qp >> 16;
    }
    atomicAdd(&aB[2 * w], alo); atomicAdd(&aB[2 * w + 1], ahi);
    atomicAdd(&pB[2 * w], plo); atomicAdd(&pB[2 * w + 1], phi);
    __syncthreads();

    if (t < 64) {
        const int l = t;
        const u32 a = aB[63 - l];     // lane l owns DESCENDING bin 63-l
        const u32 p = pB[63 - l];

        u32 ia = a, ip = p;           // inclusive scan (descending order)
        #pragma unroll
        for (int o = 1; o < 64; o <<= 1) {
            const u32 tA = __shfl_up(ia, o);
            const u32 tP = __shfl_up(ip, o);
            if (l >= o) { ia += tA; ip += tP; }
        }
        const u32 P = __shfl(ip, 63);
        const u32 T = __shfl(ia, 63);
        const float Pm = fmaxf((float)P, 1.0f);
        const float Fm = fmaxf((float)(T - P), 1.0f);

        const int cumA = (int)(ia - a), cumP = (int)(ip - p);  // exclusive
        float contrib = 0.0f;
        const int f = (int)a - (int)p;
        if (f > 0) {
            const float fpr0 = (float)(cumA - cumP) / Fm;
            if (fpr0 < MAX_FPR) {
                const float tpr0 = (float)cumP / Pm;
                const float tpr1 = (float)(cumP + (int)p) / Pm;
                const float fpr1 = (float)(cumA - cumP + f) / Fm;
                if (fpr1 <= MAX_FPR) {
                    contrib = (fpr1 - fpr0) * 0.5f * (tpr0 + tpr1);
                } else {
                    const float tfrac = (MAX_FPR - fpr0) / (fpr1 - fpr0);
                    const float tprc  = tpr0 + tfrac * (tpr1 - tpr0);
                    contrib = (MAX_FPR - fpr0) * 0.5f * (tpr0 + tprc);
                }
            }
        }
        #pragma unroll
        for (int o = 32; o; o >>= 1) contrib += __shfl_xor(contrib, o);

        int isLast = 0;
        if (l == 0) {
            paucArr[k]  = (P > 0u) ? contrib : 0.0f;   // plain stores
            validArr[k] = (P > 0u) ? 1.0f : 0.0f;
            __threadfence();
            const u32 tk = atomicAdd(doneCtr, 1u);
            isLast = (tk == NUM_CLASSES - 1);
        }
        isLast = __shfl(isLast, 0);

        if (isLast) {   // all 64 lanes gather + reduce
            float s1 = 0.0f, s2 = 0.0f, s3 = 0.0f;
            #pragma unroll
            for (int i = l; i < NUM_CLASSES; i += 64) {
                s1 += __hip_atomic_load(paucArr + i,  __ATOMIC_RELAXED,
                                        __HIP_MEMORY_SCOPE_AGENT);
                s2 += __hip_atomic_load(validArr + i, __ATOMIC_RELAXED,
                                        __HIP_MEMORY_SCOPE_AGENT);
            }
            #pragma unroll
            for (int i = l; i < NBLK; i += 64) s3 += ceArr[i];  // prev kernel
            #pragma unroll
            for (int o = 32; o; o >>= 1) {
                s1 += __shfl_xor(s1, o);
                s2 += __shfl_xor(s2, o);
                s3 += __shfl_xor(s3, o);
            }
            if (l == 0) {
                const float cem  = s3 * (1.0f / (float)N_SAMPLES);
                const float pauc = s1 / fmaxf(s2, 1.0f);
                out[0] = 0.5f * cem + 0.5f * (1.0f - pauc * pauc);
            }
        }
    }
}

extern "C" void kernel_launch(void* const* d_in, const int* in_sizes, int n_in,
                              void* d_out, int out_size, void* d_ws, size_t ws_size,
                              hipStream_t stream)
{
    const float* pred = (const float*)d_in[0];
    const int*   tgt  = (const int*)d_in[1];

    char* ws = (char*)d_ws;
    u32*   part    = (u32*)ws;                          // 16 MB partials
    float* ceArr   = (float*)(ws + 16777216);           // 2 KB
    float* paucArr = (float*)(ws + 16777216 + 2048);    // 512 B
    float* validArr= (float*)(ws + 16777216 + 2560);    // 512 B
    u32*   doneCtr = (u32*)  (ws + 16777216 + 3072);    // 4 B

    // NO memset: nothing in d_ws requires initialization (see kernel notes).
    fused_kernel<<<NBLK, 1024, 0, stream>>>(pred, tgt, part, ceArr, doneCtr);
    pauc_reduce<<<NUM_CLASSES, 256, 0, stream>>>(part, ceArr, paucArr, validArr,
                                                 doneCtr, (float*)d_out);
}